// Round 3
// baseline (4281.118 us; speedup 1.0000x reference)
//
#include <hip/hip_runtime.h>
#include <math.h>

// SentenceDecoder: B=64, D=512, H=1024, V=32000, L=2, T=32. NG = 4H = 4096.
#define BB 64
#define DD 512
#define HH 1024
#define VV 32000
#define NG 4096
#define TT 32
#define NSPLIT 8           // K-split for gate GEMMs
#define VBLK 500           // V / 64 logits tiles
#define KG (HH / 8)        // 128 k-groups of 8 per row in split layout

typedef __bf16 bf16x8 __attribute__((ext_vector_type(8)));
typedef float  f32x4  __attribute__((ext_vector_type(4)));

// split fp32 into bf16 hi + bf16 lo (RN-even both): x ~= hi + lo, err ~2^-17 rel
__device__ __forceinline__ void split_bf16(float x, unsigned short* hi, unsigned short* lo)
{
    unsigned u = __float_as_uint(x);
    unsigned r = (u + 0x7fffu + ((u >> 16) & 1u)) & 0xffff0000u;
    *hi = (unsigned short)(r >> 16);
    float rem = x - __uint_as_float(r);
    unsigned u2 = __float_as_uint(rem);
    unsigned r2 = u2 + 0x7fffu + ((u2 >> 16) & 1u);
    *lo = (unsigned short)(r2 >> 16);
}

__device__ __forceinline__ unsigned pack2(unsigned short a, unsigned short b)
{
    return (unsigned)a | ((unsigned)b << 16);
}

// ---------------------------------------------------------------------------
// split_wout_k: one-time Wout fp32 -> W2 split-bf16 fragment layout.
// W2[(row*KG + kg)*16 + {0..7 hi, 8..15 lo}], kg = k/8. One thread per (row,kg).
// Grid: V*KG/256 = 16000 blocks.
// ---------------------------------------------------------------------------
__global__ __launch_bounds__(256)
void split_wout_k(const float* __restrict__ Wout, unsigned short* __restrict__ W2)
{
    const size_t t = (size_t)blockIdx.x * 256 + threadIdx.x;   // (row,kg) id
    const float* wp = Wout + (t << 3);
    const float4 w0 = *(const float4*)wp;
    const float4 w1 = *(const float4*)(wp + 4);
    const float v[8] = {w0.x, w0.y, w0.z, w0.w, w1.x, w1.y, w1.z, w1.w};
    unsigned short hs[8], ls[8];
#pragma unroll
    for (int i = 0; i < 8; i++) split_bf16(v[i], &hs[i], &ls[i]);
    uint4 uh, ul;
    uh.x = pack2(hs[0], hs[1]); uh.y = pack2(hs[2], hs[3]);
    uh.z = pack2(hs[4], hs[5]); uh.w = pack2(hs[6], hs[7]);
    ul.x = pack2(ls[0], ls[1]); ul.y = pack2(ls[2], ls[3]);
    ul.z = pack2(ls[4], ls[5]); ul.w = pack2(ls[6], ls[7]);
    *(uint4*)(W2 + (t << 4))     = uh;
    *(uint4*)(W2 + (t << 4) + 8) = ul;
}

// ---------------------------------------------------------------------------
// gates_k: fused concat-K gate GEMM partials.
// g[b][j] (partial) = sum_{k in slice} [X|Hp][b][k] * [Wx|Wh][j][k]
// K = KX + KH, split into NSPLIT slices; 64x64 tile, 4x4 micro-tile, fp32.
// ---------------------------------------------------------------------------
__global__ __launch_bounds__(256)
void gates_k(const float* __restrict__ X, const float* __restrict__ Hp,
             const float* __restrict__ Wx, const float* __restrict__ Wh,
             int KX, int KH, float* __restrict__ P)
{
    __shared__ float As[16][68];
    __shared__ float Ws[16][68];

    const int kc  = (KX + KH) >> 3;               // slice width (multiple of 16)
    const int kk0 = blockIdx.y * kc;
    float* __restrict__ Pout = P + (size_t)blockIdx.y * (BB * NG);
    const int j0 = blockIdx.x * 64;

    const int tid = threadIdx.x;
    const int lk = tid & 15, lr = tid >> 4;
    const int tx = tid & 15, ty = tid >> 4;
    const int r0 = ty * 4, c0 = tx * 4;

    float acc[4][4] = {};

    for (int kb = kk0; kb < kk0 + kc; kb += 16) {
        const bool inX = kb < KX;                 // KX multiple of 16 -> uniform region
        const float* __restrict__ src  = inX ? X  : Hp;
        const float* __restrict__ wsrc = inX ? Wx : Wh;
        const int ksz = inX ? KX : KH;
        const int ko  = (inX ? kb : kb - KX) + lk;
#pragma unroll
        for (int i = 0; i < 4; i++) {
            As[lk][lr + 16 * i] = src[(size_t)(lr + 16 * i) * ksz + ko];
            Ws[lk][lr + 16 * i] = wsrc[(size_t)(j0 + lr + 16 * i) * ksz + ko];
        }
        __syncthreads();
#pragma unroll
        for (int kk = 0; kk < 16; kk++) {
            float4 a4 = *(const float4*)&As[kk][r0];
            float4 w4 = *(const float4*)&Ws[kk][c0];
            float av[4] = {a4.x, a4.y, a4.z, a4.w};
            float wv[4] = {w4.x, w4.y, w4.z, w4.w};
#pragma unroll
            for (int i = 0; i < 4; i++)
#pragma unroll
                for (int j = 0; j < 4; j++)
                    acc[i][j] += av[i] * wv[j];
        }
        __syncthreads();
    }

#pragma unroll
    for (int i = 0; i < 4; i++) {
        float4 o = make_float4(acc[i][0], acc[i][1], acc[i][2], acc[i][3]);
        *(float4*)&Pout[(size_t)(r0 + i) * NG + j0 + c0] = o;
    }
}

// ---------------------------------------------------------------------------
// cell_k: sum NSPLIT partial slices + biases -> gates; LSTM cell; emit h in
// split-bf16 fragment layout A2[(b*KG + kg)*16 + {hi8|lo8}] for the MFMA
// logits kernel.
// ---------------------------------------------------------------------------
__global__ __launch_bounds__(256)
void cell_k(const float* __restrict__ P, const float* __restrict__ bih,
            const float* __restrict__ bhh, float* __restrict__ h,
            float* __restrict__ c, unsigned short* __restrict__ A2)
{
    const int tid = blockIdx.x * 256 + threadIdx.x;   // B*H threads
    const int b = tid >> 10;
    const int u = tid & (HH - 1);

    float gi = bih[u]          + bhh[u];
    float gf = bih[HH + u]     + bhh[HH + u];
    float gg = bih[2 * HH + u] + bhh[2 * HH + u];
    float go = bih[3 * HH + u] + bhh[3 * HH + u];

#pragma unroll
    for (int s = 0; s < NSPLIT; s++) {
        const float* ps = P + (size_t)s * (BB * NG) + (size_t)b * NG;
        gi += ps[u];
        gf += ps[HH + u];
        gg += ps[2 * HH + u];
        go += ps[3 * HH + u];
    }

    const float si = 1.0f / (1.0f + expf(-gi));
    const float sf = 1.0f / (1.0f + expf(-gf));
    const float so = 1.0f / (1.0f + expf(-go));
    const float cn = sf * c[tid] + si * tanhf(gg);
    const float hn = so * tanhf(cn);
    c[tid] = cn;
    h[tid] = hn;

    unsigned short hi, lo;
    split_bf16(hn, &hi, &lo);
    const int kg = u >> 3, j = u & 7;
    unsigned short* o = A2 + (((size_t)b * KG + kg) << 4);
    o[j]     = hi;
    o[8 + j] = lo;
}

// ---------------------------------------------------------------------------
// logits_reg_k: 64x64 logits tile via split-bf16 MFMA, fragments read DIRECTLY
// from global (fragment-native layout) — no LDS tiles, no barriers in the
// K-loop. 3 mfma_16x16x32_bf16 per 16x16x32 step (hi*lo + lo*hi + hi*hi).
// Grid: 500 blocks x 256 thr; wave wv owns M rows [16wv,16wv+16).
// ---------------------------------------------------------------------------
__global__ __launch_bounds__(256)
void logits_reg_k(const unsigned short* __restrict__ A2,
                  const unsigned short* __restrict__ W2,
                  const float* __restrict__ bout,
                  float* __restrict__ pv, int* __restrict__ pi)
{
    __shared__ float rv[64][16];
    __shared__ int   ri[64][16];

    const int v0   = blockIdx.x * 64;
    const int tid  = threadIdx.x;
    const int wv   = tid >> 6;
    const int lane = tid & 63;
    const int l15  = lane & 15;
    const int q    = lane >> 4;

    f32x4 acc[4] = {{0,0,0,0},{0,0,0,0},{0,0,0,0},{0,0,0,0}};

    const unsigned short* pa  = A2 + (((size_t)(16 * wv + l15) * KG + q) << 4);
    const unsigned short* pw0 = W2 + (((size_t)(v0 +  0 + l15) * KG + q) << 4);
    const unsigned short* pw1 = W2 + (((size_t)(v0 + 16 + l15) * KG + q) << 4);
    const unsigned short* pw2 = W2 + (((size_t)(v0 + 32 + l15) * KG + q) << 4);
    const unsigned short* pw3 = W2 + (((size_t)(v0 + 48 + l15) * KG + q) << 4);

#pragma unroll 2
    for (int w = 0; w < 32; ++w) {
        const int off = w << 6;   // 4 kg per 32-K window, 16 ushorts per kg
        bf16x8 ah = *(const bf16x8*)(pa + off);
        bf16x8 al = *(const bf16x8*)(pa + off + 8);

        bf16x8 bh0 = *(const bf16x8*)(pw0 + off);
        bf16x8 bl0 = *(const bf16x8*)(pw0 + off + 8);
        acc[0] = __builtin_amdgcn_mfma_f32_16x16x32_bf16(ah, bl0, acc[0], 0, 0, 0);
        acc[0] = __builtin_amdgcn_mfma_f32_16x16x32_bf16(al, bh0, acc[0], 0, 0, 0);
        acc[0] = __builtin_amdgcn_mfma_f32_16x16x32_bf16(ah, bh0, acc[0], 0, 0, 0);

        bf16x8 bh1 = *(const bf16x8*)(pw1 + off);
        bf16x8 bl1 = *(const bf16x8*)(pw1 + off + 8);
        acc[1] = __builtin_amdgcn_mfma_f32_16x16x32_bf16(ah, bl1, acc[1], 0, 0, 0);
        acc[1] = __builtin_amdgcn_mfma_f32_16x16x32_bf16(al, bh1, acc[1], 0, 0, 0);
        acc[1] = __builtin_amdgcn_mfma_f32_16x16x32_bf16(ah, bh1, acc[1], 0, 0, 0);

        bf16x8 bh2 = *(const bf16x8*)(pw2 + off);
        bf16x8 bl2 = *(const bf16x8*)(pw2 + off + 8);
        acc[2] = __builtin_amdgcn_mfma_f32_16x16x32_bf16(ah, bl2, acc[2], 0, 0, 0);
        acc[2] = __builtin_amdgcn_mfma_f32_16x16x32_bf16(al, bh2, acc[2], 0, 0, 0);
        acc[2] = __builtin_amdgcn_mfma_f32_16x16x32_bf16(ah, bh2, acc[2], 0, 0, 0);

        bf16x8 bh3 = *(const bf16x8*)(pw3 + off);
        bf16x8 bl3 = *(const bf16x8*)(pw3 + off + 8);
        acc[3] = __builtin_amdgcn_mfma_f32_16x16x32_bf16(ah, bl3, acc[3], 0, 0, 0);
        acc[3] = __builtin_amdgcn_mfma_f32_16x16x32_bf16(al, bh3, acc[3], 0, 0, 0);
        acc[3] = __builtin_amdgcn_mfma_f32_16x16x32_bf16(ah, bh3, acc[3], 0, 0, 0);
    }

    // epilogue: +bias, argmax partials. C/D: col = lane&15, row = q*4 + reg.
#pragma unroll
    for (int reg = 0; reg < 4; reg++) {
        float best = -INFINITY;
        int bid = 0x7fffffff;
#pragma unroll
        for (int t = 0; t < 4; t++) {
            const int id = v0 + 16 * t + l15;
            const float v = acc[t][reg] + bout[id];
            if (v > best || (v == best && id < bid)) { best = v; bid = id; }
        }
        rv[16 * wv + q * 4 + reg][l15] = best;
        ri[16 * wv + q * 4 + reg][l15] = bid;
    }
    __syncthreads();

    if (tid < 64) {
        float best = -INFINITY;
        int bid = 0x7fffffff;
        for (int k = 0; k < 16; k++) {
            const float v = rv[tid][k];
            const int id = ri[tid][k];
            if (v > best || (v == best && id < bid)) { best = v; bid = id; }
        }
        pv[(size_t)tid * VBLK + blockIdx.x] = best;
        pi[(size_t)tid * VBLK + blockIdx.x] = bid;
    }
}

// ---------------------------------------------------------------------------
// final_k: reduce VBLK argmax partials per row -> token; gather embed row.
// ---------------------------------------------------------------------------
__global__ __launch_bounds__(256)
void final_k(const float* __restrict__ pv, const int* __restrict__ pi,
             const float* __restrict__ embed, float* __restrict__ x,
             int* __restrict__ out, int t)
{
    __shared__ float sv[256];
    __shared__ int   si[256];
    const int b = blockIdx.x;
    const int tid = threadIdx.x;

    float best = -INFINITY;
    int bid = 0x7fffffff;
    for (int k = tid; k < VBLK; k += 256) {
        float v = pv[(size_t)b * VBLK + k];
        int id = pi[(size_t)b * VBLK + k];
        if (v > best || (v == best && id < bid)) { best = v; bid = id; }
    }
    sv[tid] = best; si[tid] = bid;
    __syncthreads();
    for (int s = 128; s > 0; s >>= 1) {
        if (tid < s) {
            float v = sv[tid + s]; int id = si[tid + s];
            if (v > sv[tid] || (v == sv[tid] && id < si[tid])) { sv[tid] = v; si[tid] = id; }
        }
        __syncthreads();
    }
    const int pred = si[0];
    if (tid == 0) out[(size_t)b * TT + t] = pred;
    for (int d = tid; d < DD; d += 256)
        x[(size_t)b * DD + d] = embed[(size_t)pred * DD + d];
}

// ---------------------------------------------------------------------------
extern "C" void kernel_launch(void* const* d_in, const int* in_sizes, int n_in,
                              void* d_out, int out_size, void* d_ws, size_t ws_size,
                              hipStream_t stream)
{
    const float* features = (const float*)d_in[0];
    const float* embed    = (const float*)d_in[1];
    const float* Wih0     = (const float*)d_in[2];
    const float* Whh0     = (const float*)d_in[3];
    const float* bih0     = (const float*)d_in[4];
    const float* bhh0     = (const float*)d_in[5];
    const float* Wih1     = (const float*)d_in[6];
    const float* Whh1     = (const float*)d_in[7];
    const float* bih1     = (const float*)d_in[8];
    const float* bhh1     = (const float*)d_in[9];
    const float* Wout     = (const float*)d_in[10];
    const float* bout     = (const float*)d_in[11];
    int* out = (int*)d_out;

    // workspace layout: ~10.5 MB fp32 state + 0.5 MB A2 + 131 MB W2 (ws ~500 MB)
    float* ws   = (float*)d_ws;
    float* x    = ws;                                     // B*D
    float* h0   = x + BB * DD;                            // B*H each (h0,c0,h1,c1)
    float* c0   = h0 + BB * HH;
    float* h1   = c0 + BB * HH;
    float* c1   = h1 + BB * HH;
    float* part = c1 + BB * HH;                           // NSPLIT*B*NG
    float* pv   = part + (size_t)NSPLIT * BB * NG;        // B*VBLK
    int*   pi   = (int*)(pv + BB * VBLK);                 // B*VBLK
    unsigned short* A2_0 = (unsigned short*)(pi + BB * VBLK);  // B*H*2 ushorts each
    unsigned short* A2_1 = A2_0 + (size_t)BB * HH * 2;
    unsigned short* W2   = A2_1 + (size_t)BB * HH * 2;         // V*H*2 ushorts = 131 MB

    hipMemsetAsync(h0, 0, (size_t)4 * BB * HH * sizeof(float), stream);

    const dim3 blk(256);
    const dim3 ggate(NG / 64, NSPLIT);
    const dim3 gcell(BB * HH / 256);
    const dim3 glog(VBLK);
    const dim3 gfin(BB);

    // one-time Wout split into fragment-native layout (same work every call)
    split_wout_k<<<dim3(VV * KG / 256), blk, 0, stream>>>(Wout, W2);

    for (int t = 0; t < TT; t++) {
        const float* X0 = (t == 0) ? features : x;
        // layer 0 (fused x|h concat-K gate GEMM)
        gates_k<<<ggate, blk, 0, stream>>>(X0, h0, Wih0, Whh0, DD, HH, part);
        cell_k<<<gcell, blk, 0, stream>>>(part, bih0, bhh0, h0, c0, A2_0);
        // layer 1
        gates_k<<<ggate, blk, 0, stream>>>(h0, h1, Wih1, Whh1, HH, HH, part);
        cell_k<<<gcell, blk, 0, stream>>>(part, bih1, bhh1, h1, c1, A2_1);
        // output projection (LDS-free split-bf16 MFMA) + argmax partials
        logits_reg_k<<<glog, blk, 0, stream>>>(A2_1, W2, bout, pv, pi);
        // argmax reduce + token write + embedding gather
        final_k<<<gfin, blk, 0, stream>>>(pv, pi, embed, x, out, t);
    }
}